// Round 17
// baseline (214.036 us; speedup 1.0000x reference)
//
#include <hip/hip_runtime.h>
#include <math.h>

#define N_SAMP   32768
#define WINDOW   512
#define STEP     256
#define NFRAMES  127      // (32768-512)/256 + 1
#define NB       4
#define RTRUNC   1280     // h truncation radius (samples)
#define NSLAB    64       // mean writers/chunk = 28, 64 = +7 sigma: no overflow
#define BPAD     776      // B-copy stride (elems): 388 words = 4 mod 32 banks

// ws layout (float granularity)
#define WS_WF   0               // 4*127*512 = 260096 floats (fp32, shift conv)
#define WS_WFH  260096          // 4*64*128*8 fp16 = 131072 float slots (k-major)
#define WS_WFL  391168          // 131072 (reserved: absorbs A prefetch overrun)
#define WS_PV   522240          // 4*128*128 = 65536 (per-chunk fp16 max)
#define WS_M    587776          // 512 ints (argmax per (b,f))
#define WS_CNT  588288          // 16 ints
#define WS_LIST 588304          // 4096 ints (entry list)
#define WS_PART 592400          // nslab*4*32768 floats (per-slot partials)

typedef _Float16 f16x8 __attribute__((ext_vector_type(8)));
typedef float f32x16 __attribute__((ext_vector_type(16)));

// XOR swizzle on float4-block index (conflict-free sliding reads)
#define SW(L) ((L) ^ (((L) >> 3) & 7))

#define FMA4(A, LO, HI)                                           \
    A.x = fmaf(c.x, HI.x, A.x); A.x = fmaf(c.y, LO.w, A.x);       \
    A.x = fmaf(c.z, LO.z, A.x); A.x = fmaf(c.w, LO.y, A.x);       \
    A.y = fmaf(c.x, HI.y, A.y); A.y = fmaf(c.y, HI.x, A.y);       \
    A.y = fmaf(c.z, LO.w, A.y); A.y = fmaf(c.w, LO.z, A.y);       \
    A.z = fmaf(c.x, HI.z, A.z); A.z = fmaf(c.y, HI.y, A.z);       \
    A.z = fmaf(c.z, HI.x, A.z); A.z = fmaf(c.w, LO.w, A.z);       \
    A.w = fmaf(c.x, HI.w, A.w); A.w = fmaf(c.y, HI.z, A.w);       \
    A.w = fmaf(c.z, HI.y, A.w); A.w = fmaf(c.w, HI.x, A.w);

#define LDBLK(SH, n) (*(const float4*)((SH) + 4 * SW(Lb + (n))))

// 5-slot rolling window; coefficient c rotated with 1-deep LDS prefetch
#define CBODY(SH, g, S0, S1, S2, S3, S4)                          \
    {                                                             \
        float4 tnew = LDBLK(SH, 127 - (g) - 1);                   \
        float4 cnew = *(const float4*)(s_wc + 4 * ((g) + 1));     \
        FMA4(acc0, w[S0], w[S1]); FMA4(acc1, w[S1], w[S2]);       \
        FMA4(acc2, w[S2], w[S3]); FMA4(acc3, w[S3], w[S4]);       \
        w[S4] = tnew; c = cnew;                                   \
    }
#define CBODY_NL(g, S0, S1, S2, S3, S4)                           \
    {                                                             \
        FMA4(acc0, w[S0], w[S1]); FMA4(acc1, w[S1], w[S2]);       \
        FMA4(acc2, w[S2], w[S3]); FMA4(acc3, w[S3], w[S4]);       \
    }

#define CONV512(SH)                                               \
    {                                                             \
        float4 w[5];                                              \
        float4 c = *(const float4*)(s_wc);                        \
        w[2] = LDBLK(SH, 127); w[3] = LDBLK(SH, 128);             \
        w[4] = LDBLK(SH, 129); w[0] = LDBLK(SH, 130);             \
        w[1] = LDBLK(SH, 131);                                    \
        for (int go = 0; go < 25; ++go) {                         \
            const int gb = 5 * go;                                \
            CBODY(SH, gb + 0, 2, 3, 4, 0, 1);                     \
            CBODY(SH, gb + 1, 1, 2, 3, 4, 0);                     \
            CBODY(SH, gb + 2, 0, 1, 2, 3, 4);                     \
            CBODY(SH, gb + 3, 4, 0, 1, 2, 3);                     \
            CBODY(SH, gb + 4, 3, 4, 0, 1, 2);                     \
        }                                                         \
        CBODY(SH, 125, 2, 3, 4, 0, 1);                            \
        CBODY(SH, 126, 1, 2, 3, 4, 0);                            \
        CBODY_NL(   127, 0, 1, 2, 3, 4);                          \
    }

// ---------------------------------------------------------------- kernel A
__global__ __launch_bounds__(256) void k_wf(const float* __restrict__ recon,
                                            float* __restrict__ wf,
                                            _Float16* __restrict__ wfh) {
    int e = blockIdx.x * 256 + threadIdx.x;    // 4*128*512 exactly
    int w     = e & 511;
    int bf128 = e >> 9;
    int f = bf128 & 127;
    int b = bf128 >> 7;
    float val = 0.f;
    if (f < NFRAMES) {
        float ham = 0.54f - 0.46f * (float)cos((double)w * (M_PI / 256.0));
        val = ham * recon[b * N_SAMP + f * STEP + w];
        wf[(b * NFRAMES + f) * 512 + w] = val;
    }
    size_t tr = (((size_t)b * 64 + (w >> 3)) * 128 + f) * 8 + (w & 7);
    wfh[tr] = (_Float16)val;
}

// ---------------------------------------------------------------- kernel B
// fm = wf x Toeplitz(tgt), fp16 32x32x16 MFMA; two M-tiles per wave.
__global__ __launch_bounds__(256, 4) void k_argmax_mfma(
        const float* __restrict__ tgt,
        const _Float16* __restrict__ wfh,
        float* __restrict__ pv) {
    __shared__ _Float16 sbh[8 * BPAD];         // 12416 B
    const int tid   = threadIdx.x;
    const int chunk = blockIdx.x & 127;        // 256-t chunk
    const int half  = (blockIdx.x >> 7) & 1;   // 64-frame group
    const int b     = blockIdx.x >> 8;
    const int T0    = chunk * 256;
    const int TB    = T0 + 255;
    const float* tb = tgt + b * N_SAMP;

    for (int oc = tid; oc < 768; oc += 256) {
        int r = oc / 96, s = oc - r * 96;
        int base = TB - r - 8 * s;
        _Float16 h8[8];
#pragma unroll
        for (int j = 0; j < 8; ++j) {
            int t = base - j;
            h8[j] = (_Float16)((t >= 0) ? tb[t] : 0.0f);
        }
        *(f16x8*)&sbh[r * BPAD + 8 * s] = *(f16x8*)h8;
    }
    __syncthreads();

    const int wv  = tid >> 6;
    const int q   = (tid >> 5) & 1;
    const int cl  = tid & 31;
    const int nt0 = 2 * wv;
    const int rp  = 7 - (cl & 7);
    const _Float16* Ah0 = wfh + ((size_t)b * 64) * 1024 + (half * 64 + cl) * 8;

    f32x16 acc00 = (f32x16)(0.f);
    f32x16 acc01 = (f32x16)(0.f);
    f32x16 acc10 = (f32x16)(0.f);
    f32x16 acc11 = (f32x16)(0.f);

    int off = q * 1024;                        // k-slice q; +2048/iter
    int ea  = rp * BPAD + (255 - 32 * nt0 - cl + 8 * q - rp);
    f16x8 a0  = *(const f16x8*)(Ah0 + off);
    f16x8 a1  = *(const f16x8*)(Ah0 + off + 256);
    f16x8 bh0 = *(const f16x8*)&sbh[ea];
    f16x8 bh1 = *(const f16x8*)&sbh[ea - 32];
#pragma unroll
    for (int k0 = 0; k0 < 512; k0 += 16) {
        f16x8 a0n  = *(const f16x8*)(Ah0 + off + 2048);   // overrun -> wfl slot
        f16x8 a1n  = *(const f16x8*)(Ah0 + off + 2304);
        f16x8 bh0n = *(const f16x8*)&sbh[ea + 16];
        f16x8 bh1n = *(const f16x8*)&sbh[ea - 16];
        acc00 = __builtin_amdgcn_mfma_f32_32x32x16_f16(a0, bh0, acc00, 0, 0, 0);
        acc01 = __builtin_amdgcn_mfma_f32_32x32x16_f16(a0, bh1, acc01, 0, 0, 0);
        acc10 = __builtin_amdgcn_mfma_f32_32x32x16_f16(a1, bh0, acc10, 0, 0, 0);
        acc11 = __builtin_amdgcn_mfma_f32_32x32x16_f16(a1, bh1, acc11, 0, 0, 0);
        a0 = a0n; a1 = a1n; bh0 = bh0n; bh1 = bh1n;
        off += 2048; ea += 16;
    }

    __syncthreads();
    float* sval = (float*)sbh;                 // 64 rows x 4 waves
#pragma unroll
    for (int r = 0; r < 16; ++r) {
        float v0 = fmaxf(acc00[r], acc01[r]);
        float v1 = fmaxf(acc10[r], acc11[r]);
#pragma unroll
        for (int mm = 1; mm <= 16; mm <<= 1) {
            v0 = fmaxf(v0, __shfl_xor(v0, mm));
            v1 = fmaxf(v1, __shfl_xor(v1, mm));
        }
        if (cl == 0) {
            int row = (r & 3) + 8 * (r >> 2) + 4 * q;
            sval[row * 4 + wv]        = v0;
            sval[(32 + row) * 4 + wv] = v1;
        }
    }
    __syncthreads();
    if (tid < 64) {
        float v = fmaxf(fmaxf(sval[tid * 4], sval[tid * 4 + 1]),
                        fmaxf(sval[tid * 4 + 2], sval[tid * 4 + 3]));
        pv[((size_t)b * 128 + half * 64 + tid) * 128 + chunk] = v;
    }
}

// ---------------------------------------------------------------- kernel C
__global__ __launch_bounds__(256) void k_vmax(const float* __restrict__ tgt,
                                              const float* __restrict__ wf,
                                              const float* __restrict__ pv,
                                              int* __restrict__ marr) {
    __shared__ float wfr[512];
    __shared__ float tg[768];
    __shared__ float rv[256];
    __shared__ int   ri[256];
    __shared__ int   clist[32];
    __shared__ int   ccnt;
    const int tid = threadIdx.x;
    const int fr  = blockIdx.x;
    const int b   = fr / NFRAMES;
    const int f   = fr - b * NFRAMES;
    const float* prow = pv + ((size_t)b * 128 + f) * 128;
    const float* tb   = tgt + b * N_SAMP;

    for (int i = tid; i < 512; i += 256) wfr[i] = wf[(size_t)fr * 512 + i];

    float mv = (tid < 128) ? prow[tid] : -3.4e38f;
    rv[tid] = mv;
    __syncthreads();
    for (int s = 128; s > 0; s >>= 1) {
        if (tid < s) rv[tid] = fmaxf(rv[tid], rv[tid + s]);
        __syncthreads();
    }
    float m0 = rv[0];
    if (tid == 0) ccnt = 0;
    __syncthreads();
    float eps = 0.012f * fabsf(m0) + 1e-3f;    // covers fp16 single-product err
    if (tid < 128 && mv >= m0 - eps) {
        int k = atomicAdd(&ccnt, 1);
        if (k < 32) clist[k] = tid;
    }
    __syncthreads();
    int nc = ccnt;
    int total = (nc <= 32) ? nc : 128;         // paranoia: recheck all chunks
    float bestv = -3.4e38f; int bestt = 0x7fffffff;
    for (int ci = 0; ci < total; ++ci) {
        int c = (nc <= 32) ? clist[ci] : ci;
        int T0 = c * 256;
        __syncthreads();
        for (int y = tid; y < 768; y += 256) {
            int t = T0 - 511 + y;
            tg[y] = (t >= 0 && t < N_SAMP) ? tb[t] : 0.0f;
        }
        __syncthreads();
        float a = 0.f;
        for (int w2 = 0; w2 < 512; ++w2)
            a = fmaf(wfr[w2], tg[511 + tid - w2], a);
        int tt = T0 + tid;
        if (a > bestv || (a == bestv && tt < bestt)) { bestv = a; bestt = tt; }
    }
    rv[tid] = bestv; ri[tid] = bestt;
    __syncthreads();
    for (int s = 128; s > 0; s >>= 1) {
        if (tid < s) {
            float v2 = rv[tid + s]; int i2 = ri[tid + s];
            if (v2 > rv[tid] || (v2 == rv[tid] && i2 < ri[tid])) {
                rv[tid] = v2; ri[tid] = i2;
            }
        }
        __syncthreads();
    }
    if (tid == 0) marr[fr] = ri[0];
}

// ---------------------------------------------------------------- scheduler
__global__ __launch_bounds__(256) void k_sched(const int* __restrict__ marr,
                                               int* __restrict__ list,
                                               int* __restrict__ cnt,
                                               int nslab) {
    __shared__ int scnt[32];
    __shared__ int total;
    const int tid = threadIdx.x;
    if (tid < 32) scnt[tid] = 0;
    if (tid == 0) total = 0;
    __syncthreads();
    const int RT = RTRUNC + 16;
    for (int e = tid; e < NB * NFRAMES * 8; e += 256) {
        int bf = e >> 3, chunk = e & 7;
        int b = bf / NFRAMES;
        int t0 = chunk * 4096;
        int m = marr[bf];
        int p = (int)rint((double)m * (32768.0 / 32769.0));
        int a = (p - t0 + 512) & 65535;
        if (a < 4608 + RT || a > 65536 - RT) {
            int bc = (b << 3) | chunk;
            int s = atomicAdd(&scnt[bc], 1);
            int k = atomicAdd(&total, 1);
            list[k] = (bf << 16) | (chunk << 8) | s;
        }
    }
    __syncthreads();
    int n = total;
    for (int k = tid; k < n; k += 256) {       // whole-chunk atomic fallback
        int v = list[k];
        int bf = (v >> 16) & 0x3fff;
        int chunk = (v >> 8) & 7;
        int b = bf / NFRAMES;
        if (scnt[(b << 3) | chunk] > nslab) list[k] = v | (1 << 30);
    }
    if (tid == 0) {
        int mx = 0;
        for (int i = 0; i < 32; ++i) mx = (scnt[i] > mx) ? scnt[i] : mx;
        cnt[0] = n;
        cnt[1] = (mx > nslab) ? nslab : mx;
    }
}

// ---------------------------------------------------------------- kernel D
// h truncated at RTRUNC; wf staged in LDS; per-slot slabs (no atomics at
// nslab=64).
__global__ __launch_bounds__(256, 8) void k_shift_acc(const float* __restrict__ wf,
                                                      const int* __restrict__ marr,
                                                      const int* __restrict__ list,
                                                      const int* __restrict__ cnt,
                                                      float* __restrict__ part,
                                                      int slabmask) {
    __shared__ __align__(16) float s_h[4608];
    __shared__ __align__(16) float s_wc[512];    // total LDS 20480 B: 8 blk/CU
    const int tid = threadIdx.x;
    const int Lb  = 4 * tid;
    const int n   = cnt[0];
    const double invD = 1.0 / 2147549184.0;      // 1/(65536*32769)
    const float  sd   = 4.7936899603827e-05f;    // sin(pi/65536)
    const float  trf  = (float)(RTRUNC + 4) / 65536.0f;

    for (int e = blockIdx.x; e < n; e += gridDim.x) {
        int v     = list[e];
        int bf    = (v >> 16) & 0x3fff;
        int chunk = (v >> 8) & 7;
        int slot  = v & 255;
        int isat  = (v >> 30) & 1;
        int b     = bf / NFRAMES;
        int t0    = chunk * 4096;

        int m = marr[bf];
        double md32768 = (double)m * 32768.0;
        double sp = sin((double)m * (M_PI / 32769.0));
        float Cp = (float)(sp * (1.0 / 65536.0));
        if (m & 1) Cp = -Cp;
        float Cn = -Cp;

        float4 acc0 = make_float4(0.f, 0.f, 0.f, 0.f);
        float4 acc1 = acc0, acc2 = acc0, acc3 = acc0;

        __syncthreads();                          // prior entry's LDS reads done
        if (tid < 128)
            ((float4*)s_wc)[tid] = ((const float4*)(wf + bf * 512))[tid];
        if (m == 0) {
            for (int e4 = tid; e4 < 1152; e4 += 256) {
                int j0 = t0 - 512 + 4 * e4;
                float4 vq;
                vq.x = (j0 == 0) ? 1.0f : 0.0f;
                vq.y = 0.0f; vq.z = 0.0f; vq.w = 0.0f;
                *(float4*)(s_h + 4 * SW(e4)) = vq;
            }
        } else {
            for (int e4 = tid; e4 < 1152; e4 += 256) {
                int j0 = t0 - 512 + 4 * e4;
                double A0 = (double)j0 * 32769.0 - md32768;
                double rA0 = A0 * invD;
                float f0v = (float)(rA0 - rint(rA0));
                float4 vq;
                if (fabsf(f0v) > trf) {
                    vq = make_float4(0.f, 0.f, 0.f, 0.f);
                } else if (fabsf(f0v) < 6.2e-5f) {
#pragma unroll
                    for (int k = 0; k < 4; ++k) {
                        double rA = (A0 + (double)k * 32769.0) * invD;
                        float ff = (float)(rA - rint(rA));
                        float r;
                        if (ff == 0.0f) r = 65535.0f;
                        else {
                            float s, c2;
                            __sincosf((float)M_PI * ff, &s, &c2);
                            r = c2 * __builtin_amdgcn_rcpf(s);
                        }
                        ((float*)&vq)[k] = ((k & 1) ? Cn : Cp) * r;
                    }
                } else {
                    float s, c2;
                    __sincosf((float)M_PI * f0v, &s, &c2);
                    vq.x = Cp * (c2 * __builtin_amdgcn_rcpf(s));
                    float s1 = fmaf(c2, sd, s);
                    float c1 = fmaf(-s, sd, c2);
                    vq.y = Cn * (c1 * __builtin_amdgcn_rcpf(s1));
                    float s2 = fmaf(c1, sd, s1);
                    float cc2 = fmaf(-s1, sd, c1);
                    vq.z = Cp * (cc2 * __builtin_amdgcn_rcpf(s2));
                    float s3 = fmaf(cc2, sd, s2);
                    float c3 = fmaf(-s2, sd, cc2);
                    vq.w = Cn * (c3 * __builtin_amdgcn_rcpf(s3));
                }
                *(float4*)(s_h + 4 * SW(e4)) = vq;
            }
        }
        __syncthreads();

        CONV512(s_h)

        __syncthreads();                          // conv reads of s_h done
        *(float4*)(s_h + 4 * SW(4 * tid + 0)) = acc0;
        *(float4*)(s_h + 4 * SW(4 * tid + 1)) = acc1;
        *(float4*)(s_h + 4 * SW(4 * tid + 2)) = acc2;
        *(float4*)(s_h + 4 * SW(4 * tid + 3)) = acc3;
        __syncthreads();
        int slab = slot & slabmask;
        float* ob = part + (size_t)slab * (NB * N_SAMP) + b * N_SAMP + t0;
        if (!isat) {
#pragma unroll
            for (int k = 0; k < 4; ++k) {
                float4 vv = *(float4*)(s_h + 4 * SW(256 * k + tid));
                *(float4*)(ob + 4 * (256 * k + tid)) = vv;
            }
        } else {
#pragma unroll
            for (int k = 0; k < 4; ++k) {
                float4 vv = *(float4*)(s_h + 4 * SW(256 * k + tid));
                float* p4 = ob + 4 * (256 * k + tid);
                atomicAdd(p4 + 0, vv.x); atomicAdd(p4 + 1, vv.y);
                atomicAdd(p4 + 2, vv.z); atomicAdd(p4 + 3, vv.w);
            }
        }
    }
}

// ---------------------------------------------------------------- kernel E
__global__ __launch_bounds__(256) void k_mse(const float* __restrict__ part,
                                             const float* __restrict__ tgt,
                                             float* __restrict__ out,
                                             const int* __restrict__ cnt,
                                             int nslab) {
    __shared__ float sred[4];
    int e = blockIdx.x * 256 + threadIdx.x;
    int ng = cnt[1];
    if (ng > nslab) ng = nslab;
    float s0 = 0.f, s1 = 0.f, s2 = 0.f, s3 = 0.f;
    int g = 0;
    for (; g + 4 <= ng; g += 4) {
        s0 += part[(size_t)(g + 0) * (NB * N_SAMP) + e];
        s1 += part[(size_t)(g + 1) * (NB * N_SAMP) + e];
        s2 += part[(size_t)(g + 2) * (NB * N_SAMP) + e];
        s3 += part[(size_t)(g + 3) * (NB * N_SAMP) + e];
    }
    for (; g < ng; ++g)
        s0 += part[(size_t)g * (NB * N_SAMP) + e];
    float s = (s0 + s1) + (s2 + s3);
    float d = s - tgt[e];
    float v = d * d;
#pragma unroll
    for (int off = 32; off > 0; off >>= 1) v += __shfl_down(v, off, 64);
    int lane = threadIdx.x & 63, wid = threadIdx.x >> 6;
    if (lane == 0) sred[wid] = v;
    __syncthreads();
    if (threadIdx.x == 0) {
        float sm = sred[0] + sred[1] + sred[2] + sred[3];
        atomicAdd(out, sm * (1.0f / 131072.0f));
    }
}

// ---------------------------------------------------------------- launch
extern "C" void kernel_launch(void* const* d_in, const int* in_sizes, int n_in,
                              void* d_out, int out_size, void* d_ws, size_t ws_size,
                              hipStream_t stream) {
    const float* recon = (const float*)d_in[0];
    const float* tgt   = (const float*)d_in[1];
    float* out = (float*)d_out;
    float* W   = (float*)d_ws;

    float*     wf   = W + WS_WF;
    _Float16*  wfh  = (_Float16*)(W + WS_WFH);
    float*     pv   = W + WS_PV;
    int*       marr = (int*)(W + WS_M);
    int*       cnt  = (int*)(W + WS_CNT);
    int*       list = (int*)(W + WS_LIST);
    float*     part = W + WS_PART;

    int nslab = NSLAB;
    while (nslab > 1 &&
           ((size_t)WS_PART + (size_t)nslab * NB * N_SAMP) * sizeof(float) > ws_size)
        nslab >>= 1;

    hipMemsetAsync(out, 0, sizeof(float), stream);
    hipMemsetAsync(part, 0, (size_t)nslab * NB * N_SAMP * sizeof(float), stream);

    k_wf<<<1024, 256, 0, stream>>>(recon, wf, wfh);
    k_argmax_mfma<<<1024, 256, 0, stream>>>(tgt, wfh, pv);
    k_vmax<<<NB * NFRAMES, 256, 0, stream>>>(tgt, wf, pv, marr);
    k_sched<<<1, 256, 0, stream>>>(marr, list, cnt, nslab);
    k_shift_acc<<<2048, 256, 0, stream>>>(wf, marr, list, cnt, part, nslab - 1);
    k_mse<<<512, 256, 0, stream>>>(part, tgt, out, cnt, nslab);
}

// Round 18
// 200.064 us; speedup vs baseline: 1.0698x; 1.0698x over previous
//
#include <hip/hip_runtime.h>
#include <math.h>

#define N_SAMP   32768
#define WINDOW   512
#define STEP     256
#define NFRAMES  127      // (32768-512)/256 + 1
#define NB       4
#define RTRUNC   1280     // h truncation radius (samples)
#define NSLAB    32       // R16 best-measured config
#define BPAD     776      // B-copy stride (elems): 388 words = 4 mod 32 banks

// ws layout (float granularity)
#define WS_WF   0               // 4*127*512 = 260096 floats (fp32, shift conv)
#define WS_WFH  260096          // 4*64*128*8 fp16 = 131072 float slots (k-major)
#define WS_WFL  391168          // 131072 (reserved: absorbs A prefetch overrun)
#define WS_PV   522240          // 4*128*128 = 65536 (per-chunk fp16 max)
#define WS_M    587776          // 512 ints (argmax per (b,f))
#define WS_CNT  588288          // 16 ints
#define WS_LIST 588304          // 4096 ints (entry list)
#define WS_PART 592400          // nslab*4*32768 floats (per-slot partials)

typedef _Float16 f16x8 __attribute__((ext_vector_type(8)));
typedef float f32x16 __attribute__((ext_vector_type(16)));

// XOR swizzle on float4-block index (conflict-free sliding reads)
#define SW(L) ((L) ^ (((L) >> 3) & 7))

#define FMA4(A, LO, HI)                                           \
    A.x = fmaf(c.x, HI.x, A.x); A.x = fmaf(c.y, LO.w, A.x);       \
    A.x = fmaf(c.z, LO.z, A.x); A.x = fmaf(c.w, LO.y, A.x);       \
    A.y = fmaf(c.x, HI.y, A.y); A.y = fmaf(c.y, HI.x, A.y);       \
    A.y = fmaf(c.z, LO.w, A.y); A.y = fmaf(c.w, LO.z, A.y);       \
    A.z = fmaf(c.x, HI.z, A.z); A.z = fmaf(c.y, HI.y, A.z);       \
    A.z = fmaf(c.z, HI.x, A.z); A.z = fmaf(c.w, LO.w, A.z);       \
    A.w = fmaf(c.x, HI.w, A.w); A.w = fmaf(c.y, HI.z, A.w);       \
    A.w = fmaf(c.z, HI.y, A.w); A.w = fmaf(c.w, HI.x, A.w);

#define LDBLK(SH, n) (*(const float4*)((SH) + 4 * SW(Lb + (n))))

// 5-slot rolling window; coefficients read directly from global wc
// (scalar-cached; measured faster than LDS staging — R13 68.4 vs R14 73 us)
#define CBODY(SH, g, S0, S1, S2, S3, S4)                          \
    {                                                             \
        float4 tnew = LDBLK(SH, 127 - (g) - 1);                   \
        const float4 c = wc[(g)];                                 \
        FMA4(acc0, w[S0], w[S1]); FMA4(acc1, w[S1], w[S2]);       \
        FMA4(acc2, w[S2], w[S3]); FMA4(acc3, w[S3], w[S4]);       \
        w[S4] = tnew;                                             \
    }
#define CBODY_NL(g, S0, S1, S2, S3, S4)                           \
    {                                                             \
        const float4 c = wc[(g)];                                 \
        FMA4(acc0, w[S0], w[S1]); FMA4(acc1, w[S1], w[S2]);       \
        FMA4(acc2, w[S2], w[S3]); FMA4(acc3, w[S3], w[S4]);       \
    }

#define CONV512(SH)                                               \
    {                                                             \
        float4 w[5];                                              \
        w[2] = LDBLK(SH, 127); w[3] = LDBLK(SH, 128);             \
        w[4] = LDBLK(SH, 129); w[0] = LDBLK(SH, 130);             \
        w[1] = LDBLK(SH, 131);                                    \
        for (int go = 0; go < 25; ++go) {                         \
            const int gb = 5 * go;                                \
            CBODY(SH, gb + 0, 2, 3, 4, 0, 1);                     \
            CBODY(SH, gb + 1, 1, 2, 3, 4, 0);                     \
            CBODY(SH, gb + 2, 0, 1, 2, 3, 4);                     \
            CBODY(SH, gb + 3, 4, 0, 1, 2, 3);                     \
            CBODY(SH, gb + 4, 3, 4, 0, 1, 2);                     \
        }                                                         \
        CBODY(SH, 125, 2, 3, 4, 0, 1);                            \
        CBODY(SH, 126, 1, 2, 3, 4, 0);                            \
        CBODY_NL(   127, 0, 1, 2, 3, 4);                          \
    }

// ---------------------------------------------------------------- kernel A
__global__ __launch_bounds__(256) void k_wf(const float* __restrict__ recon,
                                            float* __restrict__ wf,
                                            _Float16* __restrict__ wfh) {
    int e = blockIdx.x * 256 + threadIdx.x;    // 4*128*512 exactly
    int w     = e & 511;
    int bf128 = e >> 9;
    int f = bf128 & 127;
    int b = bf128 >> 7;
    float val = 0.f;
    if (f < NFRAMES) {
        float ham = 0.54f - 0.46f * (float)cos((double)w * (M_PI / 256.0));
        val = ham * recon[b * N_SAMP + f * STEP + w];
        wf[(b * NFRAMES + f) * 512 + w] = val;
    }
    size_t tr = (((size_t)b * 64 + (w >> 3)) * 128 + f) * 8 + (w & 7);
    wfh[tr] = (_Float16)val;
}

// ---------------------------------------------------------------- kernel B
// fm = wf x Toeplitz(tgt), fp16 32x32x16 MFMA; two M-tiles per wave.
__global__ __launch_bounds__(256, 4) void k_argmax_mfma(
        const float* __restrict__ tgt,
        const _Float16* __restrict__ wfh,
        float* __restrict__ pv) {
    __shared__ _Float16 sbh[8 * BPAD];         // 12416 B
    const int tid   = threadIdx.x;
    const int chunk = blockIdx.x & 127;        // 256-t chunk
    const int half  = (blockIdx.x >> 7) & 1;   // 64-frame group
    const int b     = blockIdx.x >> 8;
    const int T0    = chunk * 256;
    const int TB    = T0 + 255;
    const float* tb = tgt + b * N_SAMP;

    for (int oc = tid; oc < 768; oc += 256) {
        int r = oc / 96, s = oc - r * 96;
        int base = TB - r - 8 * s;
        _Float16 h8[8];
#pragma unroll
        for (int j = 0; j < 8; ++j) {
            int t = base - j;
            h8[j] = (_Float16)((t >= 0) ? tb[t] : 0.0f);
        }
        *(f16x8*)&sbh[r * BPAD + 8 * s] = *(f16x8*)h8;
    }
    __syncthreads();

    const int wv  = tid >> 6;
    const int q   = (tid >> 5) & 1;
    const int cl  = tid & 31;
    const int nt0 = 2 * wv;
    const int rp  = 7 - (cl & 7);
    const _Float16* Ah0 = wfh + ((size_t)b * 64) * 1024 + (half * 64 + cl) * 8;

    f32x16 acc00 = (f32x16)(0.f);
    f32x16 acc01 = (f32x16)(0.f);
    f32x16 acc10 = (f32x16)(0.f);
    f32x16 acc11 = (f32x16)(0.f);

    int off = q * 1024;                        // k-slice q; +2048/iter
    int ea  = rp * BPAD + (255 - 32 * nt0 - cl + 8 * q - rp);
    f16x8 a0  = *(const f16x8*)(Ah0 + off);
    f16x8 a1  = *(const f16x8*)(Ah0 + off + 256);
    f16x8 bh0 = *(const f16x8*)&sbh[ea];
    f16x8 bh1 = *(const f16x8*)&sbh[ea - 32];
#pragma unroll
    for (int k0 = 0; k0 < 512; k0 += 16) {
        f16x8 a0n  = *(const f16x8*)(Ah0 + off + 2048);   // overrun -> wfl slot
        f16x8 a1n  = *(const f16x8*)(Ah0 + off + 2304);
        f16x8 bh0n = *(const f16x8*)&sbh[ea + 16];
        f16x8 bh1n = *(const f16x8*)&sbh[ea - 16];
        acc00 = __builtin_amdgcn_mfma_f32_32x32x16_f16(a0, bh0, acc00, 0, 0, 0);
        acc01 = __builtin_amdgcn_mfma_f32_32x32x16_f16(a0, bh1, acc01, 0, 0, 0);
        acc10 = __builtin_amdgcn_mfma_f32_32x32x16_f16(a1, bh0, acc10, 0, 0, 0);
        acc11 = __builtin_amdgcn_mfma_f32_32x32x16_f16(a1, bh1, acc11, 0, 0, 0);
        a0 = a0n; a1 = a1n; bh0 = bh0n; bh1 = bh1n;
        off += 2048; ea += 16;
    }

    __syncthreads();
    float* sval = (float*)sbh;                 // 64 rows x 4 waves
#pragma unroll
    for (int r = 0; r < 16; ++r) {
        float v0 = fmaxf(acc00[r], acc01[r]);
        float v1 = fmaxf(acc10[r], acc11[r]);
#pragma unroll
        for (int mm = 1; mm <= 16; mm <<= 1) {
            v0 = fmaxf(v0, __shfl_xor(v0, mm));
            v1 = fmaxf(v1, __shfl_xor(v1, mm));
        }
        if (cl == 0) {
            int row = (r & 3) + 8 * (r >> 2) + 4 * q;
            sval[row * 4 + wv]        = v0;
            sval[(32 + row) * 4 + wv] = v1;
        }
    }
    __syncthreads();
    if (tid < 64) {
        float v = fmaxf(fmaxf(sval[tid * 4], sval[tid * 4 + 1]),
                        fmaxf(sval[tid * 4 + 2], sval[tid * 4 + 3]));
        pv[((size_t)b * 128 + half * 64 + tid) * 128 + chunk] = v;
    }
}

// ---------------------------------------------------------------- kernel C
__global__ __launch_bounds__(256) void k_vmax(const float* __restrict__ tgt,
                                              const float* __restrict__ wf,
                                              const float* __restrict__ pv,
                                              int* __restrict__ marr) {
    __shared__ float wfr[512];
    __shared__ float tg[768];
    __shared__ float rv[256];
    __shared__ int   ri[256];
    __shared__ int   clist[32];
    __shared__ int   ccnt;
    const int tid = threadIdx.x;
    const int fr  = blockIdx.x;
    const int b   = fr / NFRAMES;
    const int f   = fr - b * NFRAMES;
    const float* prow = pv + ((size_t)b * 128 + f) * 128;
    const float* tb   = tgt + b * N_SAMP;

    for (int i = tid; i < 512; i += 256) wfr[i] = wf[(size_t)fr * 512 + i];

    float mv = (tid < 128) ? prow[tid] : -3.4e38f;
    rv[tid] = mv;
    __syncthreads();
    for (int s = 128; s > 0; s >>= 1) {
        if (tid < s) rv[tid] = fmaxf(rv[tid], rv[tid + s]);
        __syncthreads();
    }
    float m0 = rv[0];
    if (tid == 0) ccnt = 0;
    __syncthreads();
    float eps = 0.012f * fabsf(m0) + 1e-3f;    // covers fp16 single-product err
    if (tid < 128 && mv >= m0 - eps) {
        int k = atomicAdd(&ccnt, 1);
        if (k < 32) clist[k] = tid;
    }
    __syncthreads();
    int nc = ccnt;
    int total = (nc <= 32) ? nc : 128;         // paranoia: recheck all chunks
    float bestv = -3.4e38f; int bestt = 0x7fffffff;
    for (int ci = 0; ci < total; ++ci) {
        int c = (nc <= 32) ? clist[ci] : ci;
        int T0 = c * 256;
        __syncthreads();
        for (int y = tid; y < 768; y += 256) {
            int t = T0 - 511 + y;
            tg[y] = (t >= 0 && t < N_SAMP) ? tb[t] : 0.0f;
        }
        __syncthreads();
        float a = 0.f;
        for (int w2 = 0; w2 < 512; ++w2)
            a = fmaf(wfr[w2], tg[511 + tid - w2], a);
        int tt = T0 + tid;
        if (a > bestv || (a == bestv && tt < bestt)) { bestv = a; bestt = tt; }
    }
    rv[tid] = bestv; ri[tid] = bestt;
    __syncthreads();
    for (int s = 128; s > 0; s >>= 1) {
        if (tid < s) {
            float v2 = rv[tid + s]; int i2 = ri[tid + s];
            if (v2 > rv[tid] || (v2 == rv[tid] && i2 < ri[tid])) {
                rv[tid] = v2; ri[tid] = i2;
            }
        }
        __syncthreads();
    }
    if (tid == 0) marr[fr] = ri[0];
}

// ---------------------------------------------------------------- scheduler
__global__ __launch_bounds__(256) void k_sched(const int* __restrict__ marr,
                                               int* __restrict__ list,
                                               int* __restrict__ cnt,
                                               int nslab) {
    __shared__ int scnt[32];
    __shared__ int total;
    const int tid = threadIdx.x;
    if (tid < 32) scnt[tid] = 0;
    if (tid == 0) total = 0;
    __syncthreads();
    const int RT = RTRUNC + 16;
    for (int e = tid; e < NB * NFRAMES * 8; e += 256) {
        int bf = e >> 3, chunk = e & 7;
        int b = bf / NFRAMES;
        int t0 = chunk * 4096;
        int m = marr[bf];
        int p = (int)rint((double)m * (32768.0 / 32769.0));
        int a = (p - t0 + 512) & 65535;
        if (a < 4608 + RT || a > 65536 - RT) {
            int bc = (b << 3) | chunk;
            int s = atomicAdd(&scnt[bc], 1);
            int k = atomicAdd(&total, 1);
            list[k] = (bf << 16) | (chunk << 8) | s;
        }
    }
    __syncthreads();
    int n = total;
    for (int k = tid; k < n; k += 256) {       // whole-chunk atomic fallback
        int v = list[k];
        int bf = (v >> 16) & 0x3fff;
        int chunk = (v >> 8) & 7;
        int b = bf / NFRAMES;
        if (scnt[(b << 3) | chunk] > nslab) list[k] = v | (1 << 30);
    }
    if (tid == 0) {
        int mx = 0;
        for (int i = 0; i < 32; ++i) mx = (scnt[i] > mx) ? scnt[i] : mx;
        cnt[0] = n;
        cnt[1] = (mx > nslab) ? nslab : mx;
    }
}

// ---------------------------------------------------------------- kernel D
// h truncated at RTRUNC; coefficients via global scalar-cached wc (R13 form).
__global__ __launch_bounds__(256, 8) void k_shift_acc(const float* __restrict__ wf,
                                                      const int* __restrict__ marr,
                                                      const int* __restrict__ list,
                                                      const int* __restrict__ cnt,
                                                      float* __restrict__ part,
                                                      int slabmask) {
    __shared__ __align__(16) float s_h[4608];    // 18432 B: 8 blk/CU
    const int tid = threadIdx.x;
    const int Lb  = 4 * tid;
    const int n   = cnt[0];
    const double invD = 1.0 / 2147549184.0;      // 1/(65536*32769)
    const float  sd   = 4.7936899603827e-05f;    // sin(pi/65536)
    const float  trf  = (float)(RTRUNC + 4) / 65536.0f;

    for (int e = blockIdx.x; e < n; e += gridDim.x) {
        int v     = list[e];
        int bf    = (v >> 16) & 0x3fff;
        int chunk = (v >> 8) & 7;
        int slot  = v & 255;
        int isat  = (v >> 30) & 1;
        int b     = bf / NFRAMES;
        int t0    = chunk * 4096;
        const float4* __restrict__ wc = (const float4*)(wf + bf * 512);

        int m = marr[bf];
        double md32768 = (double)m * 32768.0;
        double sp = sin((double)m * (M_PI / 32769.0));
        float Cp = (float)(sp * (1.0 / 65536.0));
        if (m & 1) Cp = -Cp;
        float Cn = -Cp;

        float4 acc0 = make_float4(0.f, 0.f, 0.f, 0.f);
        float4 acc1 = acc0, acc2 = acc0, acc3 = acc0;

        __syncthreads();                          // prior entry's LDS reads done
        if (m == 0) {
            for (int e4 = tid; e4 < 1152; e4 += 256) {
                int j0 = t0 - 512 + 4 * e4;
                float4 vq;
                vq.x = (j0 == 0) ? 1.0f : 0.0f;
                vq.y = 0.0f; vq.z = 0.0f; vq.w = 0.0f;
                *(float4*)(s_h + 4 * SW(e4)) = vq;
            }
        } else {
            for (int e4 = tid; e4 < 1152; e4 += 256) {
                int j0 = t0 - 512 + 4 * e4;
                double A0 = (double)j0 * 32769.0 - md32768;
                double rA0 = A0 * invD;
                float f0v = (float)(rA0 - rint(rA0));
                float4 vq;
                if (fabsf(f0v) > trf) {
                    vq = make_float4(0.f, 0.f, 0.f, 0.f);
                } else if (fabsf(f0v) < 6.2e-5f) {
#pragma unroll
                    for (int k = 0; k < 4; ++k) {
                        double rA = (A0 + (double)k * 32769.0) * invD;
                        float ff = (float)(rA - rint(rA));
                        float r;
                        if (ff == 0.0f) r = 65535.0f;
                        else {
                            float s, c2;
                            __sincosf((float)M_PI * ff, &s, &c2);
                            r = c2 * __builtin_amdgcn_rcpf(s);
                        }
                        ((float*)&vq)[k] = ((k & 1) ? Cn : Cp) * r;
                    }
                } else {
                    float s, c2;
                    __sincosf((float)M_PI * f0v, &s, &c2);
                    vq.x = Cp * (c2 * __builtin_amdgcn_rcpf(s));
                    float s1 = fmaf(c2, sd, s);
                    float c1 = fmaf(-s, sd, c2);
                    vq.y = Cn * (c1 * __builtin_amdgcn_rcpf(s1));
                    float s2 = fmaf(c1, sd, s1);
                    float cc2 = fmaf(-s1, sd, c1);
                    vq.z = Cp * (cc2 * __builtin_amdgcn_rcpf(s2));
                    float s3 = fmaf(cc2, sd, s2);
                    float c3 = fmaf(-s2, sd, cc2);
                    vq.w = Cn * (c3 * __builtin_amdgcn_rcpf(s3));
                }
                *(float4*)(s_h + 4 * SW(e4)) = vq;
            }
        }
        __syncthreads();

        CONV512(s_h)

        __syncthreads();                          // conv reads of s_h done
        *(float4*)(s_h + 4 * SW(4 * tid + 0)) = acc0;
        *(float4*)(s_h + 4 * SW(4 * tid + 1)) = acc1;
        *(float4*)(s_h + 4 * SW(4 * tid + 2)) = acc2;
        *(float4*)(s_h + 4 * SW(4 * tid + 3)) = acc3;
        __syncthreads();
        int slab = slot & slabmask;
        float* ob = part + (size_t)slab * (NB * N_SAMP) + b * N_SAMP + t0;
        if (!isat) {
#pragma unroll
            for (int k = 0; k < 4; ++k) {
                float4 vv = *(float4*)(s_h + 4 * SW(256 * k + tid));
                *(float4*)(ob + 4 * (256 * k + tid)) = vv;
            }
        } else {
#pragma unroll
            for (int k = 0; k < 4; ++k) {
                float4 vv = *(float4*)(s_h + 4 * SW(256 * k + tid));
                float* p4 = ob + 4 * (256 * k + tid);
                atomicAdd(p4 + 0, vv.x); atomicAdd(p4 + 1, vv.y);
                atomicAdd(p4 + 2, vv.z); atomicAdd(p4 + 3, vv.w);
            }
        }
    }
}

// ---------------------------------------------------------------- kernel E
__global__ __launch_bounds__(256) void k_mse(const float* __restrict__ part,
                                             const float* __restrict__ tgt,
                                             float* __restrict__ out,
                                             const int* __restrict__ cnt,
                                             int nslab) {
    __shared__ float sred[4];
    int e = blockIdx.x * 256 + threadIdx.x;
    int ng = cnt[1];
    if (ng > nslab) ng = nslab;
    float s0 = 0.f, s1 = 0.f, s2 = 0.f, s3 = 0.f;
    int g = 0;
    for (; g + 4 <= ng; g += 4) {
        s0 += part[(size_t)(g + 0) * (NB * N_SAMP) + e];
        s1 += part[(size_t)(g + 1) * (NB * N_SAMP) + e];
        s2 += part[(size_t)(g + 2) * (NB * N_SAMP) + e];
        s3 += part[(size_t)(g + 3) * (NB * N_SAMP) + e];
    }
    for (; g < ng; ++g)
        s0 += part[(size_t)g * (NB * N_SAMP) + e];
    float s = (s0 + s1) + (s2 + s3);
    float d = s - tgt[e];
    float v = d * d;
#pragma unroll
    for (int off = 32; off > 0; off >>= 1) v += __shfl_down(v, off, 64);
    int lane = threadIdx.x & 63, wid = threadIdx.x >> 6;
    if (lane == 0) sred[wid] = v;
    __syncthreads();
    if (threadIdx.x == 0) {
        float sm = sred[0] + sred[1] + sred[2] + sred[3];
        atomicAdd(out, sm * (1.0f / 131072.0f));
    }
}

// ---------------------------------------------------------------- launch
extern "C" void kernel_launch(void* const* d_in, const int* in_sizes, int n_in,
                              void* d_out, int out_size, void* d_ws, size_t ws_size,
                              hipStream_t stream) {
    const float* recon = (const float*)d_in[0];
    const float* tgt   = (const float*)d_in[1];
    float* out = (float*)d_out;
    float* W   = (float*)d_ws;

    float*     wf   = W + WS_WF;
    _Float16*  wfh  = (_Float16*)(W + WS_WFH);
    float*     pv   = W + WS_PV;
    int*       marr = (int*)(W + WS_M);
    int*       cnt  = (int*)(W + WS_CNT);
    int*       list = (int*)(W + WS_LIST);
    float*     part = W + WS_PART;

    int nslab = NSLAB;
    while (nslab > 1 &&
           ((size_t)WS_PART + (size_t)nslab * NB * N_SAMP) * sizeof(float) > ws_size)
        nslab >>= 1;

    hipMemsetAsync(out, 0, sizeof(float), stream);
    hipMemsetAsync(part, 0, (size_t)nslab * NB * N_SAMP * sizeof(float), stream);

    k_wf<<<1024, 256, 0, stream>>>(recon, wf, wfh);
    k_argmax_mfma<<<1024, 256, 0, stream>>>(tgt, wfh, pv);
    k_vmax<<<NB * NFRAMES, 256, 0, stream>>>(tgt, wf, pv, marr);
    k_sched<<<1, 256, 0, stream>>>(marr, list, cnt, nslab);
    k_shift_acc<<<2048, 256, 0, stream>>>(wf, marr, list, cnt, part, nslab - 1);
    k_mse<<<512, 256, 0, stream>>>(part, tgt, out, cnt, nslab);
}